// Round 13
// baseline (274.291 us; speedup 1.0000x reference)
//
#include <hip/hip_runtime.h>

#define HBLK 128  // hidden width, fixed by problem
#define EPB 4096  // edges per binning block

typedef __attribute__((ext_vector_type(8))) short s8v;    // 8 bf16 in 4 VGPRs
typedef __attribute__((ext_vector_type(4))) float f32x4;  // MFMA accumulator
typedef __attribute__((ext_vector_type(8))) _Float16 h8f; // 8 fp16 = 16B

// split fp32 into bf16 hi + lo (truncation; residual <= 2^-16 |x|)
__device__ inline void split2(float x, short& h, short& l) {
    unsigned hb = __float_as_uint(x) & 0xFFFF0000u;
    float hf = __uint_as_float(hb);
    float lf = x - hf;
    h = (short)(hb >> 16);
    l = (short)(__float_as_uint(lf) >> 16);
}

__device__ inline void split8(const float4& a0, const float4& a1, s8v& ah, s8v& al) {
    float vv[8];
    *(float4*)&vv[0] = a0;
    *(float4*)&vv[4] = a1;
#pragma unroll
    for (int e = 0; e < 8; ++e) {
        short hh, ll;
        split2(vv[e], hh, ll);
        ah[e] = hh;
        al[e] = ll;
    }
}

// ================= CSR build: 2-level binning sort (no global atomics) =================
// bucket = dst >> 7 (128 nodes/bucket). ebuf entry packs (src<<7)|(dst&127) in one int.
// histT stays RAW per (bucket,block); consumers recompute the 2-level prefix locally
// (row-walk of NB1 L2-hot ints + LDS scan) -- no scan1/scan2 dispatches.

// ---- merged: edge histogram (y==0) || weight pack (y=1..5) -- fully independent ----
// Layer matrices (y-1 in 0..3) keep hi+lo split (z path feeds exp'd scores).
// y==5: concat weight, HI ONLY (bigk drops the W-lo MFMA term) + bcomb tail.
__global__ void hist_pack(const int* __restrict__ dst, int* __restrict__ histT,
                          int E, int NB1,
                          const float* __restrict__ W0, const float* __restrict__ W1,
                          const float* __restrict__ W2, const float* __restrict__ W3,
                          short* __restrict__ dh, short* __restrict__ dl,
                          const float* __restrict__ Wcat, int ldw, int mapd,
                          const float* __restrict__ Weh, int indim,
                          const float* __restrict__ beh, const float* __restrict__ bcat,
                          short* __restrict__ ch,
                          float* __restrict__ bcomb, int K) {
    __shared__ int h[256];
    const int y = blockIdx.y;
    const int t = threadIdx.x;
    if (y == 0) {
        const int blk = blockIdx.x;
        if (blk >= NB1) return;
        h[t] = 0;
        __syncthreads();
        const int e0 = blk * EPB;
        const int e1 = min(E, e0 + EPB);
        for (int e = e0 + t; e < e1; e += 256)
            atomicAdd(&h[dst[e] >> 7], 1);
        __syncthreads();
        histT[t * NB1 + blk] = h[t];
    } else if (y < 5) {
        if (blockIdx.x >= 64) return;         // 16384 elements per matrix
        const int m = y - 1;
        const long i = (long)blockIdx.x * 256 + t;
        const float* Ws[4] = {W0, W1, W2, W3};
        const int c = (int)(i >> 7), k = (int)(i & 127);
        float x = Ws[m][c * HBLK + k];
        short hh, ll;
        split2(x, hh, ll);
        const int j = c >> 4, l16 = c & 15;
        const int chunk = k >> 5, quad = (k >> 3) & 3, tt = k & 7;
        const long off = (long)m * 16384 + (((long)(chunk * 8 + j) * 64) + quad * 16 + l16) * 8 + tt;
        dh[off] = hh;
        dl[off] = ll;
    } else {
        const long i = (long)blockIdx.x * 256 + t;
        const long total = (long)HBLK * K;
        if (i < total) {
            const int c = (int)(i / K), k = (int)(i % K);
            float x = 0.f;
            if (k < mapd) {
                x = Wcat[(long)c * ldw + k];
            } else if (k < mapd + indim) {
                const float* wc = Wcat + (long)c * ldw + mapd;
                const int kk = k - mapd;
                float s = 0.f;
                for (int j = 0; j < HBLK; ++j) s += wc[j] * Weh[j * indim + kk];
                x = s;
            }
            short hh, ll;
            split2(x, hh, ll);
            const int j = c >> 4, l16 = c & 15;
            const int chunk = k >> 5, quad = (k >> 3) & 3, tt = k & 7;
            const long off = (((long)(chunk * 8 + j) * 64) + quad * 16 + l16) * 8 + tt;
            ch[off] = hh;
        } else if (i < total + HBLK) {
            const int c = (int)(i - total);
            const float* wc = Wcat + (long)c * ldw + mapd;
            float s = bcat[c];
            for (int j = 0; j < HBLK; ++j) s += wc[j] * beh[j];
            bcomb[c] = s;
        }
    }
}

// per-block local 2-level scan: thread t walks its raw histT row (NB1 ints, L2-hot),
// producing rowsum and the partial prefix up to `uptoBlk`; rowsums LDS-scanned.
__global__ void bin_scatter(const int* __restrict__ src, const int* __restrict__ dst,
                            const int* __restrict__ histT,
                            int* __restrict__ ebuf, int E, int NB1) {
    __shared__ int cur[256];
    __shared__ int tmp[256];
    const int t = threadIdx.x, blk = blockIdx.x;
    int rowsum = 0, part = 0;
    const int* row = histT + t * NB1;
    for (int b2 = 0; b2 < NB1; ++b2) {
        const int v = row[b2];
        rowsum += v;
        part += (b2 < blk) ? v : 0;
    }
    tmp[t] = rowsum;
    __syncthreads();
    for (int off = 1; off < 256; off <<= 1) {
        int add = (t >= off) ? tmp[t - off] : 0;
        __syncthreads();
        tmp[t] += add;
        __syncthreads();
    }
    cur[t] = (tmp[t] - rowsum) + part;        // global exclusive prefix for (bucket t, blk)
    __syncthreads();
    const int e0 = blk * EPB;
    const int e1 = min(E, e0 + EPB);
    for (int e = e0 + t; e < e1; e += 256) {
        const int d = dst[e];
        const int p = atomicAdd(&cur[d >> 7], 1);
        ebuf[p] = (src[e] << 7) | (d & 127);
    }
}

__global__ void bucket_sort(const int* __restrict__ ebuf, const int* __restrict__ histT,
                            int* __restrict__ offs, int* __restrict__ srcs,
                            int N, int E, int NB1) {
    __shared__ int cnt[256];
    __shared__ int cur[256];
    __shared__ int bexs[256];
    __shared__ int sums[256];
    const int t = threadIdx.x, b = blockIdx.x;
    int rowsum = 0;
    const int* row = histT + t * NB1;
    for (int b2 = 0; b2 < NB1; ++b2) rowsum += row[b2];
    cnt[t] = rowsum;
    __syncthreads();
    for (int off = 1; off < 256; off <<= 1) {
        int add = (t >= off) ? cnt[t - off] : 0;
        __syncthreads();
        cnt[t] += add;
        __syncthreads();
    }
    bexs[t] = cnt[t] - rowsum;                // bucket-level exclusive prefix
    sums[t] = rowsum;
    __syncthreads();
    const int ebase = bexs[b];
    const int eend = bexs[b] + sums[b];
    cnt[t] = 0;
    __syncthreads();
    for (int e = ebase + t; e < eend; e += 256)
        atomicAdd(&cnt[ebuf[e] & 127], 1);
    __syncthreads();
    const int own = cnt[t];
    for (int off = 1; off < 256; off <<= 1) {
        int add = (t >= off) ? cnt[t - off] : 0;
        __syncthreads();
        cnt[t] += add;
        __syncthreads();
    }
    const int excl = cnt[t] - own;
    cur[t] = ebase + excl;
    const int node = (b << 7) + t;
    if (t < 128 && node < N) offs[node] = ebase + excl;
    if (b == 0 && t == 0) offs[N] = E;
    __syncthreads();
    for (int e = ebase + t; e < eend; e += 256) {
        const int ed = ebuf[e];
        const int p = atomicAdd(&cur[ed & 127], 1);
        srcs[p] = ed >> 7;
    }
}

// ---------------- big-K MFMA GEMM (concat): BARRIER-FREE, W from L2 ----------------
// W hi-only + A split (ah*wh + al*wh). One wave (64 thr) per 16-row tile; W fragments
// stream straight from global/L2 into registers, double-buffered 2 chunks ahead;
// A prefetch 3 deep. NO LDS, NO barriers -- each wave fully independent.
__global__ __launch_bounds__(64) void gemm_bigk(
    const float* __restrict__ A1, int lda1, int K1,
    const float* __restrict__ A2, int lda2, int Kin,
    int K,
    const short* __restrict__ Wh,
    const float* __restrict__ bias,
    float* __restrict__ Cf, int M)
{
    const int lane = threadIdx.x;         // 0..63
    const int l16 = lane & 15;
    const int quad = lane >> 4;
    const int m0 = blockIdx.x * 16;
    int ra = m0 + l16;
    if (ra >= M) ra = M - 1;
    const long r1 = (long)ra * lda1;
    const long r2 = (long)ra * lda2;
    const int NC = K >> 5;

    f32x4 acc[8];
#pragma unroll
    for (int j = 0; j < 8; ++j) acc[j] = (f32x4){0.f, 0.f, 0.f, 0.f};

#define LOAD_A(d0, d1, kb)                                      \
    {                                                           \
        const int col0 = (kb) + quad * 8;                       \
        if (col0 < K1) {                                        \
            const float* ap = A1 + r1 + col0;                   \
            d0 = *(const float4*)ap;                            \
            d1 = *(const float4*)(ap + 4);                      \
        } else if (col0 < Kin) {                                \
            const float* ap = A2 + r2 + (col0 - K1);            \
            d0 = *(const float4*)ap;                            \
            d1 = *(const float4*)(ap + 4);                      \
        } else {                                                \
            d0 = make_float4(0.f, 0.f, 0.f, 0.f);               \
            d1 = make_float4(0.f, 0.f, 0.f, 0.f);               \
        }                                                       \
    }
#define LOAD_WF(dstw, c)                                                         \
    {                                                                            \
        _Pragma("unroll")                                                        \
        for (int j = 0; j < 8; ++j)                                              \
            dstw[j] = *(const s8v*)(Wh + (((long)(c) * 8 + j) * 64 + lane) * 8); \
    }
#define COMPUTE(a0, a1, wreg)                                                    \
    {                                                                            \
        s8v ah, al;                                                              \
        split8(a0, a1, ah, al);                                                  \
        _Pragma("unroll")                                                        \
        for (int j = 0; j < 8; ++j) {                                            \
            acc[j] = __builtin_amdgcn_mfma_f32_16x16x32_bf16(ah, wreg[j], acc[j], 0, 0, 0); \
            acc[j] = __builtin_amdgcn_mfma_f32_16x16x32_bf16(al, wreg[j], acc[j], 0, 0, 0); \
        }                                                                        \
    }

    s8v wA[8], wB[8];
    LOAD_WF(wA, 0)
    if (1 < NC) LOAD_WF(wB, 1)
    float4 a0c, a1c, a0n, a1n, a0p, a1p;
    LOAD_A(a0c, a1c, 0)
    LOAD_A(a0n, a1n, 32)
    LOAD_A(a0p, a1p, 64)

    for (int c = 0; c < NC; c += 2) {
        // even chunk c: wA
        COMPUTE(a0c, a1c, wA)
        if (c + 2 < NC) LOAD_WF(wA, c + 2)
        a0c = a0n; a1c = a1n;
        a0n = a0p; a1n = a1p;
        if (c + 3 < NC) LOAD_A(a0p, a1p, (c + 3) * 32)
        // odd chunk c+1: wB
        if (c + 1 < NC) {
            COMPUTE(a0c, a1c, wB)
            if (c + 3 < NC) LOAD_WF(wB, c + 3)
            a0c = a0n; a1c = a1n;
            a0n = a0p; a1n = a1p;
            if (c + 4 < NC) LOAD_A(a0p, a1p, (c + 4) * 32)
        }
    }
#undef LOAD_A
#undef LOAD_WF
#undef COMPUTE

#pragma unroll
    for (int r = 0; r < 4; ++r) {
        const int gr = m0 + quad * 4 + r;
        if (gr >= M) continue;
#pragma unroll
        for (int j = 0; j < 8; ++j) {
            const int col = j * 16 + l16;
            float v = acc[j][r] + bias[col];
            Cf[(long)gr * HBLK + col] = fmaxf(v, 0.f);
        }
    }
}

// ---------------- per-layer merged dual GEMM ----------------
// z-half keeps full split precision (feeds exp'd attention scores).
// hs-half uses Ws HI-ONLY (hs enters the output additively; err ~3e-3 abs).
__global__ __launch_bounds__(256, 2) void gemm_layer(
    const float* __restrict__ A,
    const short* __restrict__ Wsh,
    const short* __restrict__ Wfh, const short* __restrict__ Wfl,
    float* __restrict__ hsOut, _Float16* __restrict__ zOut,
    const float* __restrict__ avec,
    float* __restrict__ sOut, float* __restrict__ dOut, int M)
{
    __shared__ short lh[16384];   // 32 KB: weight hi (Wf, then Ws)
    __shared__ short ll[16384];   // 32 KB: Wf lo
    const int tid = threadIdx.x;
    const int wv = tid >> 6;
    const int lane = tid & 63;
    const int l16 = lane & 15;
    const int quad = lane >> 4;
    const int m0 = blockIdx.x * 64 + wv * 16;
    int ra = m0 + l16;
    if (ra >= M) ra = M - 1;
    const float* arow = A + (long)ra * HBLK + quad * 8;

    // stage Wf (z weight) to LDS
    {
        const int4* gh = (const int4*)Wfh;
        const int4* gl = (const int4*)Wfl;
        int4* bh = (int4*)lh;
        int4* bl = (int4*)ll;
#pragma unroll
        for (int i = 0; i < 8; ++i) {
            bh[i * 256 + tid] = gh[i * 256 + tid];
            bl[i * 256 + tid] = gl[i * 256 + tid];
        }
    }
    // A rows -> regs
    float4 aw0[4], aw1[4];
#pragma unroll
    for (int c = 0; c < 4; ++c) {
        aw0[c] = *(const float4*)(arow + c * 32);
        aw1[c] = *(const float4*)(arow + c * 32 + 4);
    }
    // Ws-hi prefetch to regs (stays outstanding through the z half)
    int4 wsh[8];
    {
        const int4* gh = (const int4*)Wsh;
#pragma unroll
        for (int i = 0; i < 8; ++i) wsh[i] = gh[i * 256 + tid];
    }
    // fragments built once, reused for both halves
    s8v ahf[4], alf[4];
#pragma unroll
    for (int c = 0; c < 4; ++c) split8(aw0[c], aw1[c], ahf[c], alf[c]);

    f32x4 acc[8];
#pragma unroll
    for (int j = 0; j < 8; ++j) acc[j] = (f32x4){0.f, 0.f, 0.f, 0.f};
    asm volatile("s_waitcnt lgkmcnt(0)" ::: "memory");
    __builtin_amdgcn_s_barrier();
    asm volatile("" ::: "memory");

    // ---- half 1: z = A @ Wf^T (full split) ----
#pragma unroll
    for (int c = 0; c < 4; ++c) {
#pragma unroll
        for (int j = 0; j < 8; ++j) {
            const s8v whf = *(const s8v*)&lh[((c * 8 + j) * 64 + lane) * 8];
            const s8v wlf = *(const s8v*)&ll[((c * 8 + j) * 64 + lane) * 8];
            acc[j] = __builtin_amdgcn_mfma_f32_16x16x32_bf16(ahf[c], whf, acc[j], 0, 0, 0);
            acc[j] = __builtin_amdgcn_mfma_f32_16x16x32_bf16(ahf[c], wlf, acc[j], 0, 0, 0);
            acc[j] = __builtin_amdgcn_mfma_f32_16x16x32_bf16(alf[c], whf, acc[j], 0, 0, 0);
        }
    }
    // C/D layout: col = lane&15, row = quad*4 + reg
#pragma unroll
    for (int r = 0; r < 4; ++r) {
        const int gr = m0 + quad * 4 + r;
        if (gr >= M) continue;
#pragma unroll
        for (int j = 0; j < 8; ++j)
            zOut[(long)gr * HBLK + j * 16 + l16] = (_Float16)acc[j][r];
    }
    // fused attention-score epilogue
    {
        float av0[8], av1[8];
#pragma unroll
        for (int j = 0; j < 8; ++j) {
            av0[j] = avec[j * 16 + l16];
            av1[j] = avec[128 + j * 16 + l16];
        }
#pragma unroll
        for (int r = 0; r < 4; ++r) {
            float ssp = 0.f, sdp = 0.f;
#pragma unroll
            for (int j = 0; j < 8; ++j) {
                const float v = acc[j][r];
                ssp += v * av0[j];
                sdp += v * av1[j];
            }
#pragma unroll
            for (int off = 1; off < 16; off <<= 1) {
                ssp += __shfl_xor(ssp, off);
                sdp += __shfl_xor(sdp, off);
            }
            const int gr = m0 + quad * 4 + r;
            if (l16 == 0 && gr < M) {
                sOut[gr] = ssp;
                dOut[gr] = sdp;
            }
        }
    }

    // ---- swap weight: all waves done reading LDS, then write Ws-hi from regs ----
    asm volatile("s_waitcnt lgkmcnt(0)" ::: "memory");
    __builtin_amdgcn_s_barrier();
    asm volatile("" ::: "memory");
    {
        int4* bh = (int4*)lh;
#pragma unroll
        for (int i = 0; i < 8; ++i) bh[i * 256 + tid] = wsh[i];
    }
    asm volatile("s_waitcnt lgkmcnt(0)" ::: "memory");
    __builtin_amdgcn_s_barrier();
    asm volatile("" ::: "memory");

    // ---- half 2: hs = A @ Ws^T (W hi-only) ----
#pragma unroll
    for (int j = 0; j < 8; ++j) acc[j] = (f32x4){0.f, 0.f, 0.f, 0.f};
#pragma unroll
    for (int c = 0; c < 4; ++c) {
#pragma unroll
        for (int j = 0; j < 8; ++j) {
            const s8v whf = *(const s8v*)&lh[((c * 8 + j) * 64 + lane) * 8];
            acc[j] = __builtin_amdgcn_mfma_f32_16x16x32_bf16(ahf[c], whf, acc[j], 0, 0, 0);
            acc[j] = __builtin_amdgcn_mfma_f32_16x16x32_bf16(alf[c], whf, acc[j], 0, 0, 0);
        }
    }
#pragma unroll
    for (int r = 0; r < 4; ++r) {
        const int gr = m0 + quad * 4 + r;
        if (gr >= M) continue;
#pragma unroll
        for (int j = 0; j < 8; ++j)
            hsOut[(long)gr * HBLK + j * 16 + l16] = acc[j][r];
    }
}

// ---------------- fused softmax + weighted gather; one wave per node ----------------
template <int FOUT>
__global__ void gat_gather(const float* __restrict__ h_in, const float* __restrict__ hs,
                           const _Float16* __restrict__ zh,
                           const float* __restrict__ s_src, const float* __restrict__ s_dst,
                           const int* __restrict__ offs, const int* __restrict__ srcs,
                           float* __restrict__ h_out,
                           const float* __restrict__ Wout, const float* __restrict__ bout,
                           float* __restrict__ outp, int OUTD, int N) {
    __shared__ float wlds[FOUT ? (32 * 132 + 4 * 132) : 4];
    const int tid = threadIdx.x;
    const int wave = tid >> 6;
    const int lane = tid & 63;
    if constexpr (FOUT) {   // stage W_out as [OUTD][132] (padded rows)
        for (int i = tid; i < OUTD * HBLK; i += 256)
            wlds[(i >> 7) * 132 + (i & 127)] = Wout[i];
        __syncthreads();
    }
    const int n = blockIdx.x * 4 + wave;
    if (n >= N) return;
    const int g = lane >> 4, l = lane & 15;
    const int beg = offs[n], end = offs[n + 1];
    const int deg = end - beg;
    const float sd = s_dst[n];                 // issued early (independent)

    // ---- early epilogue prefetch: h_in/hs rows for group 0, bias for FOUT ----
    const long base = (long)n * HBLK + 8 * l;
    float4 hi0, hi1, hv0, hv1;
    if (g == 0) {
        hi0 = *(const float4*)(h_in + base);
        hi1 = *(const float4*)(h_in + base + 4);
        if (deg > 0) {
            hv0 = *(const float4*)(hs + base);
            hv1 = *(const float4*)(hs + base + 4);
        }
    }
    float bo = 0.f;
    if constexpr (FOUT) {
        if (lane < OUTD) bo = bout[lane];
    }

    float acc[8] = {};
    if (deg > 0) {
        if (deg <= 64) {
            // ---- pass 1: one edge per lane, weight kept in-register ----
            const int sA = srcs[beg + min(lane, deg - 1)];
            float e = sd + s_src[sA];
            e = e > 0.f ? e : 0.01f * e;
            if (lane >= deg) e = -INFINITY;
            float mv = e;
#pragma unroll
            for (int off = 32; off; off >>= 1) mv = fmaxf(mv, __shfl_xor(mv, off));
            const float ex = (lane < deg) ? __expf(e - mv) : 0.f;
            float sv = ex;
#pragma unroll
            for (int off = 32; off; off >>= 1) sv += __shfl_xor(sv, off);
            const float w = ex / fmaxf(sv, 1e-16f);   // exactly 0 for lane >= deg

            // ---- pass 2: uniform trip count; group g handles idx = 4k+g ----
            const int nK = (deg + 3) >> 2;            // wave-uniform
            int k = 0;
            for (; k + 1 < nK; k += 2) {
                const int i0 = 4 * k + g;             // <= 63 always
                const int i1 = i0 + 4;
                const int s0 = __shfl(sA, i0);
                const int s1 = __shfl(sA, i1);
                const float w0 = __shfl(w, i0);
                const float w1 = __shfl(w, i1);
                const h8f z0 = *(const h8f*)(zh + (long)s0 * HBLK + 8 * l);
                const h8f z1 = *(const h8f*)(zh + (long)s1 * HBLK + 8 * l);
#pragma unroll
                for (int e2 = 0; e2 < 8; ++e2)
                    acc[e2] += w0 * (float)z0[e2] + w1 * (float)z1[e2];
            }
            if (k < nK) {
                const int i0 = 4 * k + g;
                const int s0 = __shfl(sA, i0);
                const float w0 = __shfl(w, i0);
                const h8f z0 = *(const h8f*)(zh + (long)s0 * HBLK + 8 * l);
#pragma unroll
                for (int e2 = 0; e2 < 8; ++e2)
                    acc[e2] += w0 * (float)z0[e2];
            }
        } else {
            // ---- slow path (deg > 64, rare): recompute weights ----
            float m = -INFINITY, s = 0.f;
            for (int i = beg + lane; i < end; i += 64) {
                float e = sd + s_src[srcs[i]];
                e = e > 0.f ? e : 0.01f * e;
                float nm = fmaxf(m, e);
                s = s * __expf(m - nm) + __expf(e - nm);
                m = nm;
            }
#pragma unroll
            for (int off = 32; off > 0; off >>= 1) {
                float m2 = __shfl_down(m, off);
                float s2 = __shfl_down(s, off);
                if (m2 > m) {
                    float t = m; m = m2; m2 = t;
                    float ts = s; s = s2; s2 = ts;
                }
                s = (m == -INFINITY) ? 0.f : s + s2 * __expf(m2 - m);
            }
            m = __shfl(m, 0);
            s = __shfl(s, 0);
            const float inv = 1.f / fmaxf(s, 1e-16f);
            for (int i = beg + g; i < end; i += 4) {
                const int s0 = srcs[i];
                float e0 = sd + s_src[s0];
                e0 = e0 > 0.f ? e0 : 0.01f * e0;
                const float w0 = __expf(e0 - m) * inv;
                const h8f z0 = *(const h8f*)(zh + (long)s0 * HBLK + 8 * l);
#pragma unroll
                for (int e2 = 0; e2 < 8; ++e2)
                    acc[e2] += w0 * (float)z0[e2];
            }
        }
        // combine the 4 groups (same col mapping)
#pragma unroll
        for (int e2 = 0; e2 < 8; ++e2) {
            acc[e2] += __shfl_down(acc[e2], 32);
            acc[e2] += __shfl_down(acc[e2], 16);
        }
    }

    if (g == 0) {
        float o[8];
        if (deg > 0) {
            const float* hip = (const float*)&hi0;
            const float* hvp = (const float*)&hv0;
#pragma unroll
            for (int e = 0; e < 4; ++e) o[e] = hip[e] + hvp[e] + acc[e];
            const float* hip1 = (const float*)&hi1;
            const float* hvp1 = (const float*)&hv1;
#pragma unroll
            for (int e = 0; e < 4; ++e) o[4 + e] = hip1[e] + hvp1[e] + acc[4 + e];
        } else {  // DGL leaves h at h_in; residual doubles it
            const float* hip = (const float*)&hi0;
            const float* hip1 = (const float*)&hi1;
#pragma unroll
            for (int e = 0; e < 4; ++e) o[e] = 2.f * hip[e];
#pragma unroll
            for (int e = 0; e < 4; ++e) o[4 + e] = 2.f * hip1[e];
        }
        if constexpr (FOUT) {
            float* hr = wlds + 32 * 132 + wave * 132;
            *(float4*)&hr[8 * l] = *(float4*)&o[0];
            *(float4*)&hr[8 * l + 4] = *(float4*)&o[4];
        } else {
            *(float4*)(h_out + base) = *(float4*)&o[0];
            *(float4*)(h_out + base + 4) = *(float4*)&o[4];
        }
    }
    if constexpr (FOUT) {
        // same-wave LDS FIFO: g0's ds_writes precede these ds_reads in program order
        if (lane < OUTD) {
            const float* hr = wlds + 32 * 132 + wave * 132;
            const float* wr = wlds + lane * 132;
            float a = bo;
#pragma unroll 8
            for (int k = 0; k < 32; ++k) {
                const float4 hv = *(const float4*)&hr[k * 4];
                const float4 wv = *(const float4*)&wr[k * 4];
                a += hv.x * wv.x + hv.y * wv.y + hv.z * wv.z + hv.w * wv.w;
            }
            outp[(long)n * OUTD + lane] = a;
        }
    }
}

extern "C" void kernel_launch(void* const* d_in, const int* in_sizes, int n_in,
                              void* d_out, int out_size, void* d_ws, size_t ws_size,
                              hipStream_t stream) {
    const float* feats = (const float*)d_in[0];
    const float* maps  = (const float*)d_in[2];
    const int* src = (const int*)d_in[4];
    const int* dst = (const int*)d_in[5];
    const float* W_eh  = (const float*)d_in[6];
    const float* b_eh  = (const float*)d_in[7];
    const float* W_cat = (const float*)d_in[10];
    const float* b_cat = (const float*)d_in[11];
    const float* Ws1 = (const float*)d_in[12];
    const float* Wf1 = (const float*)d_in[13];
    const float* a1  = (const float*)d_in[14];
    const float* Ws2 = (const float*)d_in[15];
    const float* Wf2 = (const float*)d_in[16];
    const float* a2  = (const float*)d_in[17];
    const float* W_out = (const float*)d_in[18];
    const float* b_out = (const float*)d_in[19];

    const int N = in_sizes[3];            // snorm_n is (N,1)
    const int E = in_sizes[4];
    const int IN_DIM = in_sizes[0] / N;   // 24
    const int MAPD = in_sizes[2] / N;     // 512
    const int OUTD = in_sizes[19];        // 24
    const int KCAT = MAPD + HBLK;         // 640 = W_cat leading dim
    const int KC = (MAPD + IN_DIM + 31) & ~31;  // 544: folded concat K, chunk-padded

    // ---- workspace layout ----
    char* p = (char*)d_ws;
    const size_t NH = (size_t)N * HBLK;
    float* hin  = (float*)p;  p += NH * 4;
    float* hs   = (float*)p;  p += NH * 4;
    float* hout = (float*)p;  p += NH * 4;
    _Float16* zh = (_Float16*)p; p += NH * 2;
    float* ssrc = (float*)p;  p += (size_t)N * 4;
    float* sdst = (float*)p;  p += (size_t)N * 4;
    int* offs   = (int*)p;    p += (size_t)(N + 1) * 4;
    int* srcs   = (int*)p;    p += (size_t)E * 4;   // src payload, dst-sorted
    int* histT  = (int*)p;    p += (size_t)256 * 256 * 4;  // RAW [bucket][block] counts
    float* bcomb = (float*)p; p += (size_t)HBLK * 4;
    p = (char*)(((uintptr_t)p + 15) & ~(uintptr_t)15);
    int* ebuf = (int*)p;      p += (size_t)E * 4;   // coarse-binned packed (src<<7)|local
    short* Wcat_h = (short*)p; p += (size_t)HBLK * KC * 2;
    short* Wly_h = (short*)p;  p += (size_t)4 * HBLK * HBLK * 2;  // 4 matrices, 16384 shorts each
    short* Wly_l = (short*)p;  p += (size_t)4 * HBLK * HBLK * 2;

    // ---- CSR hist + weight pack (merged); no scan dispatches ----
    const int NB1 = (E + EPB - 1) / EPB;       // binning blocks (<=256 for E<=1M)
    const int NBUCK = (N + 127) >> 7;          // 128-node buckets (<=256 for N<=32768)
    const int nbW = (HBLK * KC + HBLK + 255) / 256;   // 273 covers the concat pack
    const int gx = (nbW > NB1) ? nbW : NB1;
    hist_pack<<<dim3(gx, 6), 256, 0, stream>>>(
        dst, histT, E, NB1,
        Ws1, Wf1, Ws2, Wf2, Wly_h, Wly_l,
        W_cat, KCAT, MAPD, W_eh, IN_DIM, b_eh, b_cat, Wcat_h, bcomb, KC);
    bin_scatter<<<NB1, 256, 0, stream>>>(src, dst, histT, ebuf, E, NB1);
    bucket_sort<<<NBUCK, 256, 0, stream>>>(ebuf, histT, offs, srcs, N, E, NB1);

    const int gGridB = (N + 15) / 16;     // 16-row 1-wave blocks for barrier-free bigk
    const int gGrid = (N + 63) / 64;
    const int n4 = (N + 3) / 4;

    // ---- concat GEMM (front GEMM folded in): hin = relu(maps@Wc1^T + feats@Wcomb^T + bcomb)
    gemm_bigk<<<gGridB, 64, 0, stream>>>(
        maps, MAPD, MAPD, feats, IN_DIM, MAPD + IN_DIM, KC,
        Wcat_h, bcomb, hin, N);

    // ---- GAT layer 1 ----
    gemm_layer<<<gGrid, 256, 0, stream>>>(
        hin, Wly_h, Wly_h + 16384, Wly_l + 16384,
        hs, zh, a1, ssrc, sdst, N);
    gat_gather<0><<<n4, 256, 0, stream>>>(hin, hs, zh, ssrc, sdst, offs, srcs, hout,
                                          nullptr, nullptr, nullptr, OUTD, N);

    // ---- GAT layer 2 (+ fused output projection) ----
    gemm_layer<<<gGrid, 256, 0, stream>>>(
        hout, Wly_h + 32768, Wly_h + 49152, Wly_l + 49152,
        hs, zh, a2, ssrc, sdst, N);
    gat_gather<1><<<n4, 256, 0, stream>>>(hout, hs, zh, ssrc, sdst, offs, srcs, nullptr,
                                          W_out, b_out, (float*)d_out, OUTD, N);
}

// Round 14
// 247.187 us; speedup vs baseline: 1.1096x; 1.1096x over previous
//
#include <hip/hip_runtime.h>

#define HBLK 128  // hidden width, fixed by problem
#define EPB 4096  // edges per binning block

typedef __attribute__((ext_vector_type(8))) short s8v;    // 8 bf16 in 4 VGPRs
typedef __attribute__((ext_vector_type(4))) float f32x4;  // MFMA accumulator
typedef __attribute__((ext_vector_type(8))) _Float16 h8f; // 8 fp16 = 16B

// split fp32 into bf16 hi + lo (truncation; residual <= 2^-16 |x|)
__device__ inline void split2(float x, short& h, short& l) {
    unsigned hb = __float_as_uint(x) & 0xFFFF0000u;
    float hf = __uint_as_float(hb);
    float lf = x - hf;
    h = (short)(hb >> 16);
    l = (short)(__float_as_uint(lf) >> 16);
}

__device__ inline void split8(const float4& a0, const float4& a1, s8v& ah, s8v& al) {
    float vv[8];
    *(float4*)&vv[0] = a0;
    *(float4*)&vv[4] = a1;
#pragma unroll
    for (int e = 0; e < 8; ++e) {
        short hh, ll;
        split2(vv[e], hh, ll);
        ah[e] = hh;
        al[e] = ll;
    }
}

// ================= CSR build: 2-level binning sort (no global atomics) =================
// bucket = dst >> 7 (128 nodes/bucket). ebuf entry packs (src<<7)|(dst&127) in one int.
// scan2 eliminated: consumers redo the tiny (NB1<=256) bsums exclusive scan locally.

// ---- merged: edge histogram (y==0) || weight pack (y=1..5) -- fully independent ----
// Layer matrices (y-1 in 0..3) keep hi+lo split (z path feeds exp'd scores).
// y==5: concat weight, HI ONLY (bigk drops the W-lo MFMA term) + bcomb tail.
__global__ void hist_pack(const int* __restrict__ dst, int* __restrict__ histT,
                          int E, int NB1,
                          const float* __restrict__ W0, const float* __restrict__ W1,
                          const float* __restrict__ W2, const float* __restrict__ W3,
                          short* __restrict__ dh, short* __restrict__ dl,
                          const float* __restrict__ Wcat, int ldw, int mapd,
                          const float* __restrict__ Weh, int indim,
                          const float* __restrict__ beh, const float* __restrict__ bcat,
                          short* __restrict__ ch,
                          float* __restrict__ bcomb, int K) {
    __shared__ int h[256];
    const int y = blockIdx.y;
    const int t = threadIdx.x;
    if (y == 0) {
        const int blk = blockIdx.x;
        if (blk >= NB1) return;
        h[t] = 0;
        __syncthreads();
        const int e0 = blk * EPB;
        const int e1 = min(E, e0 + EPB);
        for (int e = e0 + t; e < e1; e += 256)
            atomicAdd(&h[dst[e] >> 7], 1);
        __syncthreads();
        histT[t * NB1 + blk] = h[t];
    } else if (y < 5) {
        if (blockIdx.x >= 64) return;         // 16384 elements per matrix
        const int m = y - 1;
        const long i = (long)blockIdx.x * 256 + t;
        const float* Ws[4] = {W0, W1, W2, W3};
        const int c = (int)(i >> 7), k = (int)(i & 127);
        float x = Ws[m][c * HBLK + k];
        short hh, ll;
        split2(x, hh, ll);
        const int j = c >> 4, l16 = c & 15;
        const int chunk = k >> 5, quad = (k >> 3) & 3, tt = k & 7;
        const long off = (long)m * 16384 + (((long)(chunk * 8 + j) * 64) + quad * 16 + l16) * 8 + tt;
        dh[off] = hh;
        dl[off] = ll;
    } else {
        const long i = (long)blockIdx.x * 256 + t;
        const long total = (long)HBLK * K;
        if (i < total) {
            const int c = (int)(i / K), k = (int)(i % K);
            float x = 0.f;
            if (k < mapd) {
                x = Wcat[(long)c * ldw + k];
            } else if (k < mapd + indim) {
                const float* wc = Wcat + (long)c * ldw + mapd;
                const int kk = k - mapd;
                float s = 0.f;
                for (int j = 0; j < HBLK; ++j) s += wc[j] * Weh[j * indim + kk];
                x = s;
            }
            short hh, ll;
            split2(x, hh, ll);
            const int j = c >> 4, l16 = c & 15;
            const int chunk = k >> 5, quad = (k >> 3) & 3, tt = k & 7;
            const long off = (((long)(chunk * 8 + j) * 64) + quad * 16 + l16) * 8 + tt;
            ch[off] = hh;
        } else if (i < total + HBLK) {
            const int c = (int)(i - total);
            const float* wc = Wcat + (long)c * ldw + mapd;
            float s = bcat[c];
            for (int j = 0; j < HBLK; ++j) s += wc[j] * beh[j];
            bcomb[c] = s;
        }
    }
}

__global__ void scan1(const int* __restrict__ counts, int* __restrict__ offs,
                      int* __restrict__ bsums, int n) {
    __shared__ int lds[256];
    const int t = threadIdx.x;
    const int i = blockIdx.x * 256 + t;
    const int v = (i < n) ? counts[i] : 0;
    lds[t] = v;
    __syncthreads();
    for (int off = 1; off < 256; off <<= 1) {
        int add = (t >= off) ? lds[t - off] : 0;
        __syncthreads();
        lds[t] += add;
        __syncthreads();
    }
    if (i < n) offs[i] = lds[t] - v;          // exclusive within block
    if (t == 255) bsums[blockIdx.x] = lds[255];   // RAW block totals (no scan2)
}

// in-LDS exclusive scan of the raw bsums (nb <= 256); result in bex[]
__device__ inline void local_bsum_scan(const int* __restrict__ bsums, int nb,
                                       int* bex, int* tmp) {
    const int t = threadIdx.x;
    const int v = (t < nb) ? bsums[t] : 0;
    tmp[t] = v;
    __syncthreads();
    for (int off = 1; off < 256; off <<= 1) {
        int add = (t >= off) ? tmp[t - off] : 0;
        __syncthreads();
        tmp[t] += add;
        __syncthreads();
    }
    bex[t] = tmp[t] - v;                      // exclusive prefix
    __syncthreads();
}

__global__ void bin_scatter(const int* __restrict__ src, const int* __restrict__ dst,
                            const int* __restrict__ histT, const int* __restrict__ bsums,
                            int* __restrict__ ebuf, int E, int NB1) {
    __shared__ int cur[256];
    __shared__ int bex[256];
    __shared__ int tmp[256];
    const int t = threadIdx.x, blk = blockIdx.x;
    local_bsum_scan(bsums, NB1, bex, tmp);
    const int li = t * NB1 + blk;
    cur[t] = histT[li] + bex[li >> 8];        // folded scan2+scan3
    __syncthreads();
    const int e0 = blk * EPB;
    const int e1 = min(E, e0 + EPB);
    for (int e = e0 + t; e < e1; e += 256) {
        const int d = dst[e];
        const int p = atomicAdd(&cur[d >> 7], 1);
        ebuf[p] = (src[e] << 7) | (d & 127);
    }
}

__global__ void bucket_sort(const int* __restrict__ ebuf, const int* __restrict__ histT,
                            const int* __restrict__ bsums,
                            int* __restrict__ offs, int* __restrict__ srcs,
                            int N, int E, int NB1) {
    __shared__ int cnt[256];
    __shared__ int cur[256];
    __shared__ int bex[256];
    const int t = threadIdx.x, b = blockIdx.x;
    local_bsum_scan(bsums, NB1, bex, cnt);    // cnt reused as scratch, re-init below
    const int li0 = b * NB1;
    const int ebase = histT[li0] + bex[li0 >> 8];
    int eend = E;
    if (b + 1 < 256) {
        const int li1 = (b + 1) * NB1;
        eend = histT[li1] + bex[li1 >> 8];
    }
    cnt[t] = 0;
    __syncthreads();
    for (int e = ebase + t; e < eend; e += 256)
        atomicAdd(&cnt[ebuf[e] & 127], 1);
    __syncthreads();
    const int own = cnt[t];
    for (int off = 1; off < 256; off <<= 1) {
        int add = (t >= off) ? cnt[t - off] : 0;
        __syncthreads();
        cnt[t] += add;
        __syncthreads();
    }
    const int excl = cnt[t] - own;
    cur[t] = ebase + excl;
    const int node = (b << 7) + t;
    if (t < 128 && node < N) offs[node] = ebase + excl;
    if (b == 0 && t == 0) offs[N] = E;
    __syncthreads();
    for (int e = ebase + t; e < eend; e += 256) {
        const int ed = ebuf[e];
        const int p = atomicAdd(&cur[ed & 127], 1);
        srcs[p] = ed >> 7;
    }
}

// ---------------- big-K MFMA GEMM (concat): W hi-only, A split ----------------
// Per chunk: 8KB W staged, 16 MFMAs: ah*wh + al*wh.
// 128-thread blocks (2 waves), 32 rows/block -> 626 blocks; W reg-prefetch 1 chunk
// deep, A prefetch 3 deep; raw lgkmcnt(0)+s_barrier keeps global loads in flight.
__global__ __launch_bounds__(128, 2) void gemm_bigk(
    const float* __restrict__ A1, int lda1, int K1,
    const float* __restrict__ A2, int lda2, int Kin,
    int K,
    const short* __restrict__ Wh,
    const float* __restrict__ bias,
    float* __restrict__ Cf, int M)
{
    __shared__ short lds_h[2][4096];
    const int tid = threadIdx.x;          // 0..127
    const int wv = tid >> 6;              // 0..1
    const int lane = tid & 63;
    const int l16 = lane & 15;
    const int quad = lane >> 4;
    const int m0 = blockIdx.x * 32 + wv * 16;
    int ra = m0 + l16;
    if (ra >= M) ra = M - 1;
    const long r1 = (long)ra * lda1;
    const long r2 = (long)ra * lda2;
    const int NC = K >> 5;

    f32x4 acc[8];
#pragma unroll
    for (int j = 0; j < 8; ++j) acc[j] = (f32x4){0.f, 0.f, 0.f, 0.f};

#define LOAD_A(d0, d1, kb)                                      \
    {                                                           \
        const int col0 = (kb) + quad * 8;                       \
        if (col0 < K1) {                                        \
            const float* ap = A1 + r1 + col0;                   \
            d0 = *(const float4*)ap;                            \
            d1 = *(const float4*)(ap + 4);                      \
        } else if (col0 < Kin) {                                \
            const float* ap = A2 + r2 + (col0 - K1);            \
            d0 = *(const float4*)ap;                            \
            d1 = *(const float4*)(ap + 4);                      \
        } else {                                                \
            d0 = make_float4(0.f, 0.f, 0.f, 0.f);               \
            d1 = make_float4(0.f, 0.f, 0.f, 0.f);               \
        }                                                       \
    }
#define LOAD_W(c)                                               \
    {                                                           \
        const int4* gh = (const int4*)(Wh + (long)(c) * 4096);  \
        wh0 = gh[tid * 4];     wh1 = gh[tid * 4 + 1];           \
        wh2 = gh[tid * 4 + 2]; wh3 = gh[tid * 4 + 3];           \
    }
#define WRITE_W(b)                                              \
    {                                                           \
        int4* bh = (int4*)lds_h[b];                             \
        bh[tid * 4] = wh0;     bh[tid * 4 + 1] = wh1;           \
        bh[tid * 4 + 2] = wh2; bh[tid * 4 + 3] = wh3;           \
    }

    int4 wh0, wh1, wh2, wh3;
    LOAD_W(0)
    WRITE_W(0)
    LOAD_W(1)                               // chunk 1 held in regs until end of c=0
    float4 a0c, a1c, a0n, a1n, a0p, a1p;
    float4 a0q = make_float4(0.f, 0.f, 0.f, 0.f);
    float4 a1q = make_float4(0.f, 0.f, 0.f, 0.f);
    LOAD_A(a0c, a1c, 0)
    LOAD_A(a0n, a1n, 32)
    LOAD_A(a0p, a1p, 64)
    asm volatile("s_waitcnt lgkmcnt(0)" ::: "memory");
    __builtin_amdgcn_s_barrier();
    asm volatile("" ::: "memory");

    for (int c = 0; c < NC; ++c) {
        const int nb = c & 1;
        if (c + 3 < NC) {
            LOAD_A(a0q, a1q, (c + 3) * 32)
        }
        s8v ah, al;
        split8(a0c, a1c, ah, al);
#pragma unroll
        for (int j = 0; j < 8; ++j) {
            const s8v whf = *(const s8v*)&lds_h[nb][(j * 64 + lane) * 8];
            acc[j] = __builtin_amdgcn_mfma_f32_16x16x32_bf16(ah, whf, acc[j], 0, 0, 0);
            acc[j] = __builtin_amdgcn_mfma_f32_16x16x32_bf16(al, whf, acc[j], 0, 0, 0);
        }
        if (c + 1 < NC) {
            WRITE_W(nb ^ 1)                 // stage chunk c+1 (regs); vmcnt auto-waited
            if (c + 2 < NC) LOAD_W(c + 2)   // prefetch chunk c+2 into regs
            asm volatile("s_waitcnt lgkmcnt(0)" ::: "memory");
            __builtin_amdgcn_s_barrier();
            asm volatile("" ::: "memory");
        }
        a0c = a0n; a1c = a1n;
        a0n = a0p; a1n = a1p;
        a0p = a0q; a1p = a1q;
    }
#undef LOAD_A
#undef LOAD_W
#undef WRITE_W

#pragma unroll
    for (int r = 0; r < 4; ++r) {
        const int gr = m0 + quad * 4 + r;
        if (gr >= M) continue;
#pragma unroll
        for (int j = 0; j < 8; ++j) {
            const int col = j * 16 + l16;
            float v = acc[j][r] + bias[col];
            Cf[(long)gr * HBLK + col] = fmaxf(v, 0.f);
        }
    }
}

// ---------------- per-layer merged dual GEMM ----------------
// z-half keeps full split precision (feeds exp'd attention scores).
// hs-half uses Ws HI-ONLY (hs enters the output additively; err ~3e-3 abs):
// half the Ws prefetch regs + swap-stage ds_writes, 64 vs 96 MFMAs.
__global__ __launch_bounds__(256, 2) void gemm_layer(
    const float* __restrict__ A,
    const short* __restrict__ Wsh,
    const short* __restrict__ Wfh, const short* __restrict__ Wfl,
    float* __restrict__ hsOut, _Float16* __restrict__ zOut,
    const float* __restrict__ avec,
    float* __restrict__ sOut, float* __restrict__ dOut, int M)
{
    __shared__ short lh[16384];   // 32 KB: weight hi (Wf, then Ws)
    __shared__ short ll[16384];   // 32 KB: Wf lo
    const int tid = threadIdx.x;
    const int wv = tid >> 6;
    const int lane = tid & 63;
    const int l16 = lane & 15;
    const int quad = lane >> 4;
    const int m0 = blockIdx.x * 64 + wv * 16;
    int ra = m0 + l16;
    if (ra >= M) ra = M - 1;
    const float* arow = A + (long)ra * HBLK + quad * 8;

    // stage Wf (z weight) to LDS
    {
        const int4* gh = (const int4*)Wfh;
        const int4* gl = (const int4*)Wfl;
        int4* bh = (int4*)lh;
        int4* bl = (int4*)ll;
#pragma unroll
        for (int i = 0; i < 8; ++i) {
            bh[i * 256 + tid] = gh[i * 256 + tid];
            bl[i * 256 + tid] = gl[i * 256 + tid];
        }
    }
    // A rows -> regs
    float4 aw0[4], aw1[4];
#pragma unroll
    for (int c = 0; c < 4; ++c) {
        aw0[c] = *(const float4*)(arow + c * 32);
        aw1[c] = *(const float4*)(arow + c * 32 + 4);
    }
    // Ws-hi prefetch to regs (stays outstanding through the z half)
    int4 wsh[8];
    {
        const int4* gh = (const int4*)Wsh;
#pragma unroll
        for (int i = 0; i < 8; ++i) wsh[i] = gh[i * 256 + tid];
    }
    // fragments built once, reused for both halves
    s8v ahf[4], alf[4];
#pragma unroll
    for (int c = 0; c < 4; ++c) split8(aw0[c], aw1[c], ahf[c], alf[c]);

    f32x4 acc[8];
#pragma unroll
    for (int j = 0; j < 8; ++j) acc[j] = (f32x4){0.f, 0.f, 0.f, 0.f};
    asm volatile("s_waitcnt lgkmcnt(0)" ::: "memory");
    __builtin_amdgcn_s_barrier();
    asm volatile("" ::: "memory");

    // ---- half 1: z = A @ Wf^T (full split) ----
#pragma unroll
    for (int c = 0; c < 4; ++c) {
#pragma unroll
        for (int j = 0; j < 8; ++j) {
            const s8v whf = *(const s8v*)&lh[((c * 8 + j) * 64 + lane) * 8];
            const s8v wlf = *(const s8v*)&ll[((c * 8 + j) * 64 + lane) * 8];
            acc[j] = __builtin_amdgcn_mfma_f32_16x16x32_bf16(ahf[c], whf, acc[j], 0, 0, 0);
            acc[j] = __builtin_amdgcn_mfma_f32_16x16x32_bf16(ahf[c], wlf, acc[j], 0, 0, 0);
            acc[j] = __builtin_amdgcn_mfma_f32_16x16x32_bf16(alf[c], whf, acc[j], 0, 0, 0);
        }
    }
    // C/D layout: col = lane&15, row = quad*4 + reg
#pragma unroll
    for (int r = 0; r < 4; ++r) {
        const int gr = m0 + quad * 4 + r;
        if (gr >= M) continue;
#pragma unroll
        for (int j = 0; j < 8; ++j)
            zOut[(long)gr * HBLK + j * 16 + l16] = (_Float16)acc[j][r];
    }
    // fused attention-score epilogue
    {
        float av0[8], av1[8];
#pragma unroll
        for (int j = 0; j < 8; ++j) {
            av0[j] = avec[j * 16 + l16];
            av1[j] = avec[128 + j * 16 + l16];
        }
#pragma unroll
        for (int r = 0; r < 4; ++r) {
            float ssp = 0.f, sdp = 0.f;
#pragma unroll
            for (int j = 0; j < 8; ++j) {
                const float v = acc[j][r];
                ssp += v * av0[j];
                sdp += v * av1[j];
            }
#pragma unroll
            for (int off = 1; off < 16; off <<= 1) {
                ssp += __shfl_xor(ssp, off);
                sdp += __shfl_xor(sdp, off);
            }
            const int gr = m0 + quad * 4 + r;
            if (l16 == 0 && gr < M) {
                sOut[gr] = ssp;
                dOut[gr] = sdp;
            }
        }
    }

    // ---- swap weight: all waves done reading LDS, then write Ws-hi from regs ----
    asm volatile("s_waitcnt lgkmcnt(0)" ::: "memory");
    __builtin_amdgcn_s_barrier();
    asm volatile("" ::: "memory");
    {
        int4* bh = (int4*)lh;
#pragma unroll
        for (int i = 0; i < 8; ++i) bh[i * 256 + tid] = wsh[i];
    }
    asm volatile("s_waitcnt lgkmcnt(0)" ::: "memory");
    __builtin_amdgcn_s_barrier();
    asm volatile("" ::: "memory");

    // ---- half 2: hs = A @ Ws^T (W hi-only) ----
#pragma unroll
    for (int j = 0; j < 8; ++j) acc[j] = (f32x4){0.f, 0.f, 0.f, 0.f};
#pragma unroll
    for (int c = 0; c < 4; ++c) {
#pragma unroll
        for (int j = 0; j < 8; ++j) {
            const s8v whf = *(const s8v*)&lh[((c * 8 + j) * 64 + lane) * 8];
            acc[j] = __builtin_amdgcn_mfma_f32_16x16x32_bf16(ahf[c], whf, acc[j], 0, 0, 0);
            acc[j] = __builtin_amdgcn_mfma_f32_16x16x32_bf16(alf[c], whf, acc[j], 0, 0, 0);
        }
    }
#pragma unroll
    for (int r = 0; r < 4; ++r) {
        const int gr = m0 + quad * 4 + r;
        if (gr >= M) continue;
#pragma unroll
        for (int j = 0; j < 8; ++j)
            hsOut[(long)gr * HBLK + j * 16 + l16] = acc[j][r];
    }
}

// ---------------- fused softmax + weighted gather; one wave per node ----------------
template <int FOUT>
__global__ void gat_gather(const float* __restrict__ h_in, const float* __restrict__ hs,
                           const _Float16* __restrict__ zh,
                           const float* __restrict__ s_src, const float* __restrict__ s_dst,
                           const int* __restrict__ offs, const int* __restrict__ srcs,
                           float* __restrict__ h_out,
                           const float* __restrict__ Wout, const float* __restrict__ bout,
                           float* __restrict__ outp, int OUTD, int N) {
    __shared__ float wlds[FOUT ? (32 * 132 + 4 * 132) : 4];
    const int tid = threadIdx.x;
    const int wave = tid >> 6;
    const int lane = tid & 63;
    if constexpr (FOUT) {   // stage W_out as [OUTD][132] (padded rows)
        for (int i = tid; i < OUTD * HBLK; i += 256)
            wlds[(i >> 7) * 132 + (i & 127)] = Wout[i];
        __syncthreads();
    }
    const int n = blockIdx.x * 4 + wave;
    if (n >= N) return;
    const int g = lane >> 4, l = lane & 15;
    const int beg = offs[n], end = offs[n + 1];
    const int deg = end - beg;
    const float sd = s_dst[n];                 // issued early (independent)

    // ---- early epilogue prefetch: h_in/hs rows for group 0, bias for FOUT ----
    const long base = (long)n * HBLK + 8 * l;
    float4 hi0, hi1, hv0, hv1;
    if (g == 0) {
        hi0 = *(const float4*)(h_in + base);
        hi1 = *(const float4*)(h_in + base + 4);
        if (deg > 0) {
            hv0 = *(const float4*)(hs + base);
            hv1 = *(const float4*)(hs + base + 4);
        }
    }
    float bo = 0.f;
    if constexpr (FOUT) {
        if (lane < OUTD) bo = bout[lane];
    }

    float acc[8] = {};
    if (deg > 0) {
        if (deg <= 64) {
            // ---- pass 1: one edge per lane, weight kept in-register ----
            const int sA = srcs[beg + min(lane, deg - 1)];
            float e = sd + s_src[sA];
            e = e > 0.f ? e : 0.01f * e;
            if (lane >= deg) e = -INFINITY;
            float mv = e;
#pragma unroll
            for (int off = 32; off; off >>= 1) mv = fmaxf(mv, __shfl_xor(mv, off));
            const float ex = (lane < deg) ? __expf(e - mv) : 0.f;
            float sv = ex;
#pragma unroll
            for (int off = 32; off; off >>= 1) sv += __shfl_xor(sv, off);
            const float w = ex / fmaxf(sv, 1e-16f);   // exactly 0 for lane >= deg

            // ---- pass 2: uniform trip count; group g handles idx = 4k+g ----
            const int nK = (deg + 3) >> 2;            // wave-uniform
            int k = 0;
            for (; k + 1 < nK; k += 2) {
                const int i0 = 4 * k + g;             // <= 63 always
                const int i1 = i0 + 4;
                const int s0 = __shfl(sA, i0);
                const int s1 = __shfl(sA, i1);
                const float w0 = __shfl(w, i0);
                const float w1 = __shfl(w, i1);
                const h8f z0 = *(const h8f*)(zh + (long)s0 * HBLK + 8 * l);
                const h8f z1 = *(const h8f*)(zh + (long)s1 * HBLK + 8 * l);
#pragma unroll
                for (int e2 = 0; e2 < 8; ++e2)
                    acc[e2] += w0 * (float)z0[e2] + w1 * (float)z1[e2];
            }
            if (k < nK) {
                const int i0 = 4 * k + g;
                const int s0 = __shfl(sA, i0);
                const float w0 = __shfl(w, i0);
                const h8f z0 = *(const h8f*)(zh + (long)s0 * HBLK + 8 * l);
#pragma unroll
                for (int e2 = 0; e2 < 8; ++e2)
                    acc[e2] += w0 * (float)z0[e2];
            }
        } else {
            // ---- slow path (deg > 64, rare): recompute weights ----
            float m = -INFINITY, s = 0.f;
            for (int i = beg + lane; i < end; i += 64) {
                float e = sd + s_src[srcs[i]];
                e = e > 0.f ? e : 0.01f * e;
                float nm = fmaxf(m, e);
                s = s * __expf(m - nm) + __expf(e - nm);
                m = nm;
            }
#pragma unroll
            for (int off = 32; off > 0; off >>= 1) {
                float m2 = __shfl_down(m, off);
                float s2 = __shfl_down(s, off);
                if (m2 > m) {
                    float t = m; m = m2; m2 = t;
                    float ts = s; s = s2; s2 = ts;
                }
                s = (m == -INFINITY) ? 0.f : s + s2 * __expf(m2 - m);
            }
            m = __shfl(m, 0);
            s = __shfl(s, 0);
            const float inv = 1.f / fmaxf(s, 1e-16f);
            for (int i = beg + g; i < end; i += 4) {
                const int s0 = srcs[i];
                float e0 = sd + s_src[s0];
                e0 = e0 > 0.f ? e0 : 0.01f * e0;
                const float w0 = __expf(e0 - m) * inv;
                const h8f z0 = *(const h8f*)(zh + (long)s0 * HBLK + 8 * l);
#pragma unroll
                for (int e2 = 0; e2 < 8; ++e2)
                    acc[e2] += w0 * (float)z0[e2];
            }
        }
        // combine the 4 groups (same col mapping)
#pragma unroll
        for (int e2 = 0; e2 < 8; ++e2) {
            acc[e2] += __shfl_down(acc[e2], 32);
            acc[e2] += __shfl_down(acc[e2], 16);
        }
    }

    if (g == 0) {
        float o[8];
        if (deg > 0) {
            const float* hip = (const float*)&hi0;
            const float* hvp = (const float*)&hv0;
#pragma unroll
            for (int e = 0; e < 4; ++e) o[e] = hip[e] + hvp[e] + acc[e];
            const float* hip1 = (const float*)&hi1;
            const float* hvp1 = (const float*)&hv1;
#pragma unroll
            for (int e = 0; e < 4; ++e) o[4 + e] = hip1[e] + hvp1[e] + acc[4 + e];
        } else {  // DGL leaves h at h_in; residual doubles it
            const float* hip = (const float*)&hi0;
            const float* hip1 = (const float*)&hi1;
#pragma unroll
            for (int e = 0; e < 4; ++e) o[e] = 2.f * hip[e];
#pragma unroll
            for (int e = 0; e < 4; ++e) o[4 + e] = 2.f * hip1[e];
        }
        if constexpr (FOUT) {
            float* hr = wlds + 32 * 132 + wave * 132;
            *(float4*)&hr[8 * l] = *(float4*)&o[0];
            *(float4*)&hr[8 * l + 4] = *(float4*)&o[4];
        } else {
            *(float4*)(h_out + base) = *(float4*)&o[0];
            *(float4*)(h_out + base + 4) = *(float4*)&o[4];
        }
    }
    if constexpr (FOUT) {
        // same-wave LDS FIFO: g0's ds_writes precede these ds_reads in program order
        if (lane < OUTD) {
            const float* hr = wlds + 32 * 132 + wave * 132;
            const float* wr = wlds + lane * 132;
            float a = bo;
#pragma unroll 8
            for (int k = 0; k < 32; ++k) {
                const float4 hv = *(const float4*)&hr[k * 4];
                const float4 wv = *(const float4*)&wr[k * 4];
                a += hv.x * wv.x + hv.y * wv.y + hv.z * wv.z + hv.w * wv.w;
            }
            outp[(long)n * OUTD + lane] = a;
        }
    }
}

extern "C" void kernel_launch(void* const* d_in, const int* in_sizes, int n_in,
                              void* d_out, int out_size, void* d_ws, size_t ws_size,
                              hipStream_t stream) {
    const float* feats = (const float*)d_in[0];
    const float* maps  = (const float*)d_in[2];
    const int* src = (const int*)d_in[4];
    const int* dst = (const int*)d_in[5];
    const float* W_eh  = (const float*)d_in[6];
    const float* b_eh  = (const float*)d_in[7];
    const float* W_cat = (const float*)d_in[10];
    const float* b_cat = (const float*)d_in[11];
    const float* Ws1 = (const float*)d_in[12];
    const float* Wf1 = (const float*)d_in[13];
    const float* a1  = (const float*)d_in[14];
    const float* Ws2 = (const float*)d_in[15];
    const float* Wf2 = (const float*)d_in[16];
    const float* a2  = (const float*)d_in[17];
    const float* W_out = (const float*)d_in[18];
    const float* b_out = (const float*)d_in[19];

    const int N = in_sizes[3];            // snorm_n is (N,1)
    const int E = in_sizes[4];
    const int IN_DIM = in_sizes[0] / N;   // 24
    const int MAPD = in_sizes[2] / N;     // 512
    const int OUTD = in_sizes[19];        // 24
    const int KCAT = MAPD + HBLK;         // 640 = W_cat leading dim
    const int KC = (MAPD + IN_DIM + 31) & ~31;  // 544: folded concat K, chunk-padded

    // ---- workspace layout ----
    char* p = (char*)d_ws;
    const size_t NH = (size_t)N * HBLK;
    float* hin  = (float*)p;  p += NH * 4;
    float* hs   = (float*)p;  p += NH * 4;
    float* hout = (float*)p;  p += NH * 4;
    _Float16* zh = (_Float16*)p; p += NH * 2;
    float* ssrc = (float*)p;  p += (size_t)N * 4;
    float* sdst = (float*)p;  p += (size_t)N * 4;
    int* offs   = (int*)p;    p += (size_t)(N + 1) * 4;
    int* srcs   = (int*)p;    p += (size_t)E * 4;   // src payload, dst-sorted
    int* bsums  = (int*)p;    p += 256 * 4;
    int* histT  = (int*)p;    p += (size_t)256 * 256 * 4;  // [bucket][block] scanned counts
    float* bcomb = (float*)p; p += (size_t)HBLK * 4;
    p = (char*)(((uintptr_t)p + 15) & ~(uintptr_t)15);
    int* ebuf = (int*)p;      p += (size_t)E * 4;   // coarse-binned packed (src<<7)|local
    short* Wcat_h = (short*)p; p += (size_t)HBLK * KC * 2;
    short* Wly_h = (short*)p;  p += (size_t)4 * HBLK * HBLK * 2;  // 4 matrices, 16384 shorts each
    short* Wly_l = (short*)p;  p += (size_t)4 * HBLK * HBLK * 2;

    // ---- CSR hist + weight pack (merged, independent work) ----
    const int NB1 = (E + EPB - 1) / EPB;       // binning blocks (<=256 for E<=1M)
    const int NBUCK = (N + 127) >> 7;          // 128-node buckets (<=256 for N<=32768)
    const int nHist = 256 * NB1;
    const int nbW = (HBLK * KC + HBLK + 255) / 256;   // 273 covers the concat pack
    const int gx = (nbW > NB1) ? nbW : NB1;
    hist_pack<<<dim3(gx, 6), 256, 0, stream>>>(
        dst, histT, E, NB1,
        Ws1, Wf1, Ws2, Wf2, Wly_h, Wly_l,
        W_cat, KCAT, MAPD, W_eh, IN_DIM, b_eh, b_cat, Wcat_h, bcomb, KC);
    scan1<<<NB1, 256, 0, stream>>>(histT, histT, bsums, nHist);
    bin_scatter<<<NB1, 256, 0, stream>>>(src, dst, histT, bsums, ebuf, E, NB1);
    bucket_sort<<<NBUCK, 256, 0, stream>>>(ebuf, histT, bsums, offs, srcs, N, E, NB1);

    const int gGridB = (N + 31) / 32;     // 32-row blocks for bigk (TLP)
    const int gGrid = (N + 63) / 64;
    const int n4 = (N + 3) / 4;

    // ---- concat GEMM (front GEMM folded in): hin = relu(maps@Wc1^T + feats@Wcomb^T + bcomb)
    gemm_bigk<<<gGridB, 128, 0, stream>>>(
        maps, MAPD, MAPD, feats, IN_DIM, MAPD + IN_DIM, KC,
        Wcat_h, bcomb, hin, N);

    // ---- GAT layer 1 ----
    gemm_layer<<<gGrid, 256, 0, stream>>>(
        hin, Wly_h, Wly_h + 16384, Wly_l + 16384,
        hs, zh, a1, ssrc, sdst, N);
    gat_gather<0><<<n4, 256, 0, stream>>>(hin, hs, zh, ssrc, sdst, offs, srcs, hout,
                                          nullptr, nullptr, nullptr, OUTD, N);

    // ---- GAT layer 2 (+ fused output projection) ----
    gemm_layer<<<gGrid, 256, 0, stream>>>(
        hout, Wly_h + 32768, Wly_h + 49152, Wly_l + 49152,
        hs, zh, a2, ssrc, sdst, N);
    gat_gather<1><<<n4, 256, 0, stream>>>(hout, hs, zh, ssrc, sdst, offs, srcs, nullptr,
                                          W_out, b_out, (float*)d_out, OUTD, N);
}